// Round 2
// baseline (158.448 us; speedup 1.0000x reference)
//
#include <hip/hip_runtime.h>

#define TLEN 512
#define KLEN 11
#define XPAD_L 80          // covers idx >= -75 (pad <= 75)
#define XTOT 752           // covers idx <= 661 (511 + 10*15); 80+512+160
// LDS: 752 * 16 B = 12032 B

__device__ __forceinline__ float wave_max_f32(float v) {
    const int NEG_INF = 0xFF800000;           // -inf bit pattern (identity for max)
    int x = __float_as_int(v);
    int t;
    t = __builtin_amdgcn_update_dpp(NEG_INF, x, 0x111, 0xF, 0xF, false); // row_shr:1
    x = __float_as_int(fmaxf(__int_as_float(x), __int_as_float(t)));
    t = __builtin_amdgcn_update_dpp(NEG_INF, x, 0x112, 0xF, 0xF, false); // row_shr:2
    x = __float_as_int(fmaxf(__int_as_float(x), __int_as_float(t)));
    t = __builtin_amdgcn_update_dpp(NEG_INF, x, 0x114, 0xF, 0xF, false); // row_shr:4
    x = __float_as_int(fmaxf(__int_as_float(x), __int_as_float(t)));
    t = __builtin_amdgcn_update_dpp(NEG_INF, x, 0x118, 0xF, 0xF, false); // row_shr:8
    x = __float_as_int(fmaxf(__int_as_float(x), __int_as_float(t)));
    t = __builtin_amdgcn_update_dpp(NEG_INF, x, 0x142, 0xA, 0xF, false); // row_bcast:15
    x = __float_as_int(fmaxf(__int_as_float(x), __int_as_float(t)));
    t = __builtin_amdgcn_update_dpp(NEG_INF, x, 0x143, 0xC, 0xF, false); // row_bcast:31
    x = __float_as_int(fmaxf(__int_as_float(x), __int_as_float(t)));
    return __int_as_float(__builtin_amdgcn_readlane(x, 63));            // full-wave max
}

__global__ __launch_bounds__(256) void rf_kernel(
    const float* __restrict__ x, const float* __restrict__ weight,
    const float* __restrict__ bias, const int* __restrict__ dilation,
    const int* __restrict__ padding, const int* __restrict__ out_len,
    float* __restrict__ out, int K)
{
    __shared__ float4 xs[XTOT];
    const int t = threadIdx.x;
    const int b0 = blockIdx.y * 4;

    // --- stage: 4 batches interleaved as float4, zero-padded both sides ---
    const float4 z4 = make_float4(0.f, 0.f, 0.f, 0.f);
    if (t < XPAD_L) xs[t] = z4;                                  // left pad [0,80)
    if (t >= 80 && t < 240) xs[XPAD_L + TLEN + (t - 80)] = z4;   // right pad, 160 slots
    const float* x0 = x + (size_t)b0 * TLEN;
    xs[XPAD_L + t] = make_float4(x0[t], x0[TLEN + t], x0[2 * TLEN + t], x0[3 * TLEN + t]);
    xs[XPAD_L + 256 + t] = make_float4(x0[256 + t], x0[TLEN + 256 + t],
                                       x0[2 * TLEN + 256 + t], x0[3 * TLEN + 256 + t]);
    __syncthreads();

    const int wave = t >> 6;
    const int lane = t & 63;
    const int k = blockIdx.x * 4 + wave;

    const int dil  = dilation[k];
    const int pd   = padding[k];
    const int olen = out_len[k];
    const float bs = bias[k];
    const float* wk = weight + k * KLEN;

    float4 acc[8];
    #pragma unroll
    for (int i = 0; i < 8; ++i) acc[i] = z4;

    int s = XPAD_L + lane - pd;
    #pragma unroll
    for (int j = 0; j < KLEN; ++j) {
        const float wj = wk[j];
        const float4* xp = xs + s;
        #pragma unroll
        for (int i = 0; i < 8; ++i) {
            float4 v = xp[64 * i];                 // ds_read_b128, imm offset 1024*i
            acc[i].x = fmaf(wj, v.x, acc[i].x);
            acc[i].y = fmaf(wj, v.y, acc[i].y);
            acc[i].z = fmaf(wj, v.z, acc[i].z);
            acc[i].w = fmaf(wj, v.w, acc[i].w);
        }
        s += dil;
    }

    // --- epilogue: max via DPP (VALU), count via ballot (SALU) ---
    float4 mx = make_float4(-INFINITY, -INFINITY, -INFINITY, -INFINITY);
    int c0 = 0, c1 = 0, c2 = 0, c3 = 0;
    #pragma unroll
    for (int i = 0; i < 8; ++i) {
        const int p0 = i * 64;
        float4 c;
        c.x = acc[i].x + bs; c.y = acc[i].y + bs;
        c.z = acc[i].z + bs; c.w = acc[i].w + bs;
        if (p0 + 64 <= olen) {                     // fully-valid chunk (uniform branch)
            mx.x = fmaxf(mx.x, c.x); mx.y = fmaxf(mx.y, c.y);
            mx.z = fmaxf(mx.z, c.z); mx.w = fmaxf(mx.w, c.w);
            c0 += __popcll(__ballot(c.x > 0.f));
            c1 += __popcll(__ballot(c.y > 0.f));
            c2 += __popcll(__ballot(c.z > 0.f));
            c3 += __popcll(__ballot(c.w > 0.f));
        } else if (p0 < olen) {                    // boundary chunk
            const bool vld = lane < (olen - p0);
            mx.x = fmaxf(mx.x, vld ? c.x : -INFINITY);
            mx.y = fmaxf(mx.y, vld ? c.y : -INFINITY);
            mx.z = fmaxf(mx.z, vld ? c.z : -INFINITY);
            mx.w = fmaxf(mx.w, vld ? c.w : -INFINITY);
            c0 += __popcll(__ballot(vld && c.x > 0.f));
            c1 += __popcll(__ballot(vld && c.y > 0.f));
            c2 += __popcll(__ballot(vld && c.z > 0.f));
            c3 += __popcll(__ballot(vld && c.w > 0.f));
        }
    }

    mx.x = wave_max_f32(mx.x);
    mx.y = wave_max_f32(mx.y);
    mx.z = wave_max_f32(mx.z);
    mx.w = wave_max_f32(mx.w);

    if (lane == 0) {
        const float inv = 1.0f / (float)olen;
        const size_t row = (size_t)2 * K;
        float* o = out + (size_t)b0 * row + 2 * k;
        o[0]           = mx.x;  o[1]           = (float)c0 * inv;
        o[row]         = mx.y;  o[row + 1]     = (float)c1 * inv;
        o[2 * row]     = mx.z;  o[2 * row + 1] = (float)c2 * inv;
        o[3 * row]     = mx.w;  o[3 * row + 1] = (float)c3 * inv;
    }
}

extern "C" void kernel_launch(void* const* d_in, const int* in_sizes, int n_in,
                              void* d_out, int out_size, void* d_ws, size_t ws_size,
                              hipStream_t stream) {
    const float* x    = (const float*)d_in[0];
    const float* w    = (const float*)d_in[1];
    const float* bias = (const float*)d_in[2];
    const int* dil    = (const int*)d_in[3];
    const int* pad    = (const int*)d_in[4];
    const int* olen   = (const int*)d_in[5];
    float* out        = (float*)d_out;

    const int K = in_sizes[2];          // 4096
    const int B = in_sizes[0] / TLEN;   // 32

    dim3 grid(K / 4, B / 4);            // 1024 x 8 = 8192 blocks, 4 waves each
    rf_kernel<<<grid, 256, 0, stream>>>(x, w, bias, dil, pad, olen, out, K);
}

// Round 3
// 99.034 us; speedup vs baseline: 1.5999x; 1.5999x over previous
//
#include <hip/hip_runtime.h>

#define TLEN 512
#define KLEN 11
#define XPAD 256          // covers idx >= -255 (pad <= 255 worst case)
#define XTOT 1024         // covers idx <  768 (valid-p max idx = 511 + pad <= 766)
// LDS: 1024 * 16 B = 16 KiB

__device__ __forceinline__ float wave_max_f32(float v) {
    const int NEG_INF = 0xFF800000;           // -inf bits (identity for max)
    int x = __float_as_int(v);
    int t;
    t = __builtin_amdgcn_update_dpp(NEG_INF, x, 0x111, 0xF, 0xF, false); // row_shr:1
    x = __float_as_int(fmaxf(__int_as_float(x), __int_as_float(t)));
    t = __builtin_amdgcn_update_dpp(NEG_INF, x, 0x112, 0xF, 0xF, false); // row_shr:2
    x = __float_as_int(fmaxf(__int_as_float(x), __int_as_float(t)));
    t = __builtin_amdgcn_update_dpp(NEG_INF, x, 0x114, 0xF, 0xF, false); // row_shr:4
    x = __float_as_int(fmaxf(__int_as_float(x), __int_as_float(t)));
    t = __builtin_amdgcn_update_dpp(NEG_INF, x, 0x118, 0xF, 0xF, false); // row_shr:8
    x = __float_as_int(fmaxf(__int_as_float(x), __int_as_float(t)));
    t = __builtin_amdgcn_update_dpp(NEG_INF, x, 0x142, 0xA, 0xF, false); // row_bcast:15
    x = __float_as_int(fmaxf(__int_as_float(x), __int_as_float(t)));
    t = __builtin_amdgcn_update_dpp(NEG_INF, x, 0x143, 0xC, 0xF, false); // row_bcast:31
    x = __float_as_int(fmaxf(__int_as_float(x), __int_as_float(t)));
    return __int_as_float(__builtin_amdgcn_readlane(x, 63));
}

__global__ __launch_bounds__(256, 4) void rf_kernel(
    const float* __restrict__ x, const float* __restrict__ weight,
    const float* __restrict__ bias, const int* __restrict__ dilation,
    const int* __restrict__ padding, const int* __restrict__ out_len,
    float* __restrict__ out, int K)
{
    __shared__ float4 xs[XTOT];
    const int t = threadIdx.x;
    const int b0 = blockIdx.y * 4;

    // --- stage: 4 batches interleaved per float4 slot, zero-padded both sides ---
    const float4 z4 = make_float4(0.f, 0.f, 0.f, 0.f);
    xs[t] = z4;                    // left pad  [0, 256)
    xs[768 + t] = z4;              // right pad [768, 1024)
    const float* x0 = x + (size_t)b0 * TLEN;
    xs[XPAD + t]       = make_float4(x0[t],       x0[TLEN + t],
                                     x0[2 * TLEN + t],       x0[3 * TLEN + t]);
    xs[XPAD + 256 + t] = make_float4(x0[256 + t], x0[TLEN + 256 + t],
                                     x0[2 * TLEN + 256 + t], x0[3 * TLEN + 256 + t]);
    __syncthreads();

    const int lane = t & 63;
    // force k scalar so dil/pad/olen/bias/weights live in SGPRs
    const int ks = __builtin_amdgcn_readfirstlane(blockIdx.x * 4 + (t >> 6));

    const int dil  = dilation[ks];
    const int pd   = padding[ks];
    const int olen = out_len[ks];
    const float bs = bias[ks];
    float wj[KLEN];
    #pragma unroll
    for (int j = 0; j < KLEN; ++j) wj[j] = weight[ks * KLEN + j];

    const int base = XPAD + lane - pd;   // one VGPR; + j*dil (scalar) + 64*i (imm)

    float4 mx = make_float4(-INFINITY, -INFINITY, -INFINITY, -INFINITY);
    int c0 = 0, c1 = 0, c2 = 0, c3 = 0;

    #pragma unroll
    for (int i = 0; i < 8; ++i) {
        const int p0 = i * 64;
        if (p0 < olen) {                               // uniform: skip dead chunks
            float4 a = z4;
            #pragma unroll
            for (int j = 0; j < KLEN; ++j) {
                if (wj[j] != 0.0f) {                   // uniform: skip zero taps
                    const float4 v = xs[base + j * dil + p0];
                    a.x = fmaf(wj[j], v.x, a.x);
                    a.y = fmaf(wj[j], v.y, a.y);
                    a.z = fmaf(wj[j], v.z, a.z);
                    a.w = fmaf(wj[j], v.w, a.w);
                }
            }
            a.x += bs; a.y += bs; a.z += bs; a.w += bs;
            if (p0 + 64 <= olen) {                     // fully-valid chunk
                mx.x = fmaxf(mx.x, a.x); mx.y = fmaxf(mx.y, a.y);
                mx.z = fmaxf(mx.z, a.z); mx.w = fmaxf(mx.w, a.w);
                c0 += __popcll(__ballot(a.x > 0.f));
                c1 += __popcll(__ballot(a.y > 0.f));
                c2 += __popcll(__ballot(a.z > 0.f));
                c3 += __popcll(__ballot(a.w > 0.f));
            } else {                                   // boundary chunk
                const bool vld = lane < (olen - p0);
                mx.x = fmaxf(mx.x, vld ? a.x : -INFINITY);
                mx.y = fmaxf(mx.y, vld ? a.y : -INFINITY);
                mx.z = fmaxf(mx.z, vld ? a.z : -INFINITY);
                mx.w = fmaxf(mx.w, vld ? a.w : -INFINITY);
                c0 += __popcll(__ballot(vld && a.x > 0.f));
                c1 += __popcll(__ballot(vld && a.y > 0.f));
                c2 += __popcll(__ballot(vld && a.z > 0.f));
                c3 += __popcll(__ballot(vld && a.w > 0.f));
            }
        }
    }

    mx.x = wave_max_f32(mx.x);
    mx.y = wave_max_f32(mx.y);
    mx.z = wave_max_f32(mx.z);
    mx.w = wave_max_f32(mx.w);

    if (lane == 0) {
        const float inv = 1.0f / (float)olen;
        const size_t row = (size_t)2 * K;
        float* o = out + (size_t)b0 * row + 2 * ks;
        *(float2*)(o)           = make_float2(mx.x, (float)c0 * inv);
        *(float2*)(o + row)     = make_float2(mx.y, (float)c1 * inv);
        *(float2*)(o + 2 * row) = make_float2(mx.z, (float)c2 * inv);
        *(float2*)(o + 3 * row) = make_float2(mx.w, (float)c3 * inv);
    }
}

extern "C" void kernel_launch(void* const* d_in, const int* in_sizes, int n_in,
                              void* d_out, int out_size, void* d_ws, size_t ws_size,
                              hipStream_t stream) {
    const float* x    = (const float*)d_in[0];
    const float* w    = (const float*)d_in[1];
    const float* bias = (const float*)d_in[2];
    const int* dil    = (const int*)d_in[3];
    const int* pad    = (const int*)d_in[4];
    const int* olen   = (const int*)d_in[5];
    float* out        = (float*)d_out;

    const int K = in_sizes[2];          // 4096
    const int B = in_sizes[0] / TLEN;   // 32

    dim3 grid(K / 4, B / 4);            // 1024 x 8 blocks, 4 waves each
    rf_kernel<<<grid, 256, 0, stream>>>(x, w, bias, dil, pad, olen, out, K);
}